// Round 3
// baseline (79.552 us; speedup 1.0000x reference)
//
#include <hip/hip_runtime.h>
#include <hip/hip_bf16.h>
#include <math.h>

#define B_DIM 64
#define D_DIM 256
#define C_DIM 100000
#define P_DIM 8
#define N_DIM 32
#define NTILE 3125      // C_DIM / 32
#define NBANK 16        // exp-sum accumulator banks (atomic contention spread)

typedef __attribute__((ext_vector_type(8))) short bf16x8;
typedef __attribute__((ext_vector_type(16))) float f32x16;

__device__ __forceinline__ unsigned short bf16_rn(float f) {
    unsigned int u = __float_as_uint(f);
    unsigned int r = (u + 0x7FFFu + ((u >> 16) & 1u)) >> 16;
    return (unsigned short)r;
}

// Truncate-split: x = hi + lo (hi exact truncation, lo rounds; combined ~2^-17 rel err)
__device__ __forceinline__ void split_bf16(float x, unsigned short& hi, unsigned short& lo) {
    unsigned int bx = __float_as_uint(x);
    unsigned int hb = bx & 0xFFFF0000u;
    hi = (unsigned short)(hb >> 16);
    lo = bf16_rn(x - __uint_as_float(hb));
}

__device__ __forceinline__ float softplusf(float x) { return log1pf(expf(x)); }

__device__ __forceinline__ short f2bf(float x) {
    __hip_bfloat16 b = __float2bfloat16(x);   // compiler pairs these into v_cvt_pk_bf16_f32
    return *reinterpret_cast<short*>(&b);
}

// ---------------- Kernel A: norms, sim = ni@ni^T (hi+lo MFMA), hp/hn losses, A-frag precompute ----------------
__global__ __launch_bounds__(256)
void prep_kernel(const float* __restrict__ X,
                 const int* __restrict__ pos_idx, const int* __restrict__ pos_mask,
                 const int* __restrict__ neg_idx, const int* __restrict__ neg_mask,
                 float* __restrict__ wsH, unsigned short* __restrict__ wsA,
                 float* __restrict__ wsQ) {
    __shared__ unsigned short fHi[2048 * 8];   // 32 KB: ni hi fragments (frag order)
    __shared__ unsigned short fLo[2048 * 8];   // 32 KB
    __shared__ float sim[64][64];              // 16 KB
    __shared__ float inv[64];
    __shared__ float hp[64];
    __shared__ float contrib[64];
    const int tid = threadIdx.x;
    // zero the banked exp-sum accumulators (atomics accumulate into them each call)
    #pragma unroll
    for (int i = tid; i < NBANK * 64; i += 256) wsQ[i] = 0.0f;
    // row norms: 4 threads per row
    {
        int r = tid >> 2, q = tid & 3;
        const float* row = X + r * D_DIM + q * 64;
        float s = 0.0f;
        #pragma unroll
        for (int i = 0; i < 64; i += 4) {
            float4 v = *(const float4*)(row + i);
            s += v.x * v.x + v.y * v.y + v.z * v.z + v.w * v.w;
        }
        s += __shfl_xor(s, 1);
        s += __shfl_xor(s, 2);
        if (q == 0) inv[r] = 1.0f / fmaxf(sqrtf(s), 1e-12f);
    }
    __syncthreads();
    // fragments: lane l holds M[mt*32+(l&31)][kg*16+8*(l>>5)+j]
    for (int t = tid; t < 2048; t += 256) {
        int l = t & 63, kg = (t >> 6) & 15, mt = t >> 10;
        int row = mt * 32 + (l & 31);
        int col0 = kg * 16 + 8 * (l >> 5);
        const float* src = X + row * D_DIM + col0;
        float iv = inv[row];
        #pragma unroll
        for (int j = 0; j < 8; ++j) {
            unsigned short h, lo;
            split_bf16(src[j] * iv, h, lo);
            fHi[t * 8 + j] = h;
            fLo[t * 8 + j] = lo;
            wsA[t * 8 + j] = (unsigned short)f2bf(src[j]);  // raw-X fragment for logits kernel
        }
    }
    __syncthreads();
    // sim via 4 wave tiles of 32x32 (A-frag and B-frag layouts coincide for ni@ni^T)
    {
        int w = tid >> 6, l = tid & 63;
        int mt = w >> 1, nt = w & 1;
        f32x16 acc;
        #pragma unroll
        for (int i = 0; i < 16; ++i) acc[i] = 0.0f;
        #pragma unroll
        for (int ks = 0; ks < 16; ++ks) {
            const bf16x8 ah = *(const bf16x8*)&fHi[((mt * 16 + ks) * 64 + l) * 8];
            const bf16x8 al = *(const bf16x8*)&fLo[((mt * 16 + ks) * 64 + l) * 8];
            const bf16x8 bh = *(const bf16x8*)&fHi[((nt * 16 + ks) * 64 + l) * 8];
            const bf16x8 bl = *(const bf16x8*)&fLo[((nt * 16 + ks) * 64 + l) * 8];
            acc = __builtin_amdgcn_mfma_f32_32x32x16_bf16(ah, bh, acc, 0, 0, 0);
            acc = __builtin_amdgcn_mfma_f32_32x32x16_bf16(al, bh, acc, 0, 0, 0);
            acc = __builtin_amdgcn_mfma_f32_32x32x16_bf16(ah, bl, acc, 0, 0, 0);
        }
        #pragma unroll
        for (int r = 0; r < 16; ++r) {
            int brow = mt * 32 + (r & 3) + 8 * (r >> 2) + 4 * (l >> 5);
            int bcol = nt * 32 + (l & 31);
            sim[brow][bcol] = acc[r];
        }
    }
    __syncthreads();
    // hardest positive: min over valid positive pairs (>=1 guaranteed)
    {
        int r = tid >> 2, q = tid & 3;
        const float INF = __int_as_float(0x7f800000);
        float m = INF;
        #pragma unroll
        for (int pp = 0; pp < 2; ++pp) {
            int p = q * 2 + pp;
            int j = pos_idx[r * P_DIM + p];
            int msk = pos_mask[r * P_DIM + p];
            float ps = sim[r][j];
            m = fminf(m, msk ? ps : INF);
        }
        m = fminf(m, __shfl_xor(m, 1));
        m = fminf(m, __shfl_xor(m, 2));
        if (q == 0) hp[r] = m;
    }
    __syncthreads();
    // hard negatives
    {
        int r = tid >> 2, q = tid & 3;
        float thr = hp[r] - 0.3f;
        float sum = 0.0f; int cnt = 0;
        #pragma unroll
        for (int nn = 0; nn < 8; ++nn) {
            int n = q * 8 + nn;
            int j = neg_idx[r * N_DIM + n];
            int msk = neg_mask[r * N_DIM + n];
            float ns = sim[r][j];
            if (msk && (ns > thr)) { cnt += 1; sum += softplusf(ns); }
        }
        sum += __shfl_xor(sum, 1); cnt += __shfl_xor(cnt, 1);
        sum += __shfl_xor(sum, 2); cnt += __shfl_xor(cnt, 2);
        if (q == 0) {
            float hn = (cnt > 0) ? (sum / (float)cnt) : 0.0f;
            contrib[r] = softplusf(-hp[r]) + hn;
        }
    }
    __syncthreads();
    if (tid == 0) {
        float s = 0.0f;
        for (int i = 0; i < 64; ++i) s += contrib[i];
        wsH[0] = s * (1.0f / 64.0f);
    }
}

// ---------------- Kernel B: logits = X @ V^T, 2-wave K-split, fused exp-sum epilogue ----------------
// Block = 128 thr (2 waves), tile = 32 columns of V, full M=64.
// Wave w covers K in [w*128, w*128+128); epilogue: wave w owns output rows mt==w.
__global__ __launch_bounds__(128, 4)
void logits_kernel(const float* __restrict__ V, const unsigned short* __restrict__ wsA,
                   float* __restrict__ out, float* __restrict__ wsQ) {
    __shared__ float red[2][16][65];           // 8.3 KB cross-wave exchange, conflict-free
    const int tid = threadIdx.x;
    const int w = tid >> 6, l = tid & 63;
    const int c0 = blockIdx.x * 32;
    const int c = c0 + (l & 31);
    const float* vbase = V + (size_t)c * D_DIM + w * 128 + 8 * (l >> 5);

    f32x16 acc0, acc1;                         // mt = 0, 1
    #pragma unroll
    for (int i = 0; i < 16; ++i) { acc0[i] = 0.0f; acc1[i] = 0.0f; }

    #pragma unroll
    for (int half = 0; half < 2; ++half) {
        // batch the 8 V loads + 8 A-frag loads (single latency exposure per half)
        float4 vA[8];
        #pragma unroll
        for (int ks = 0; ks < 4; ++ks) {
            int kk = half * 4 + ks;
            vA[ks * 2]     = *(const float4*)(vbase + kk * 16);
            vA[ks * 2 + 1] = *(const float4*)(vbase + kk * 16 + 4);
        }
        bf16x8 a0[4], a1[4];
        #pragma unroll
        for (int ks = 0; ks < 4; ++ks) {
            int kg = w * 8 + half * 4 + ks;
            a0[ks] = *(const bf16x8*)(wsA + ((0 * 16 + kg) * 64 + l) * 8);
            a1[ks] = *(const bf16x8*)(wsA + ((1 * 16 + kg) * 64 + l) * 8);
        }
        #pragma unroll
        for (int ks = 0; ks < 4; ++ks) {
            float4 r0 = vA[ks * 2], r1 = vA[ks * 2 + 1];
            bf16x8 vh;
            vh[0] = f2bf(r0.x); vh[1] = f2bf(r0.y); vh[2] = f2bf(r0.z); vh[3] = f2bf(r0.w);
            vh[4] = f2bf(r1.x); vh[5] = f2bf(r1.y); vh[6] = f2bf(r1.z); vh[7] = f2bf(r1.w);
            acc0 = __builtin_amdgcn_mfma_f32_32x32x16_bf16(a0[ks], vh, acc0, 0, 0, 0);
            acc1 = __builtin_amdgcn_mfma_f32_32x32x16_bf16(a1[ks], vh, acc1, 0, 0, 0);
        }
    }

    // cross-wave exchange: wave w shares its partial for the OTHER mt
    if (w == 0) {
        #pragma unroll
        for (int r = 0; r < 16; ++r) red[0][r][l] = acc1[r];
    } else {
        #pragma unroll
        for (int r = 0; r < 16; ++r) red[1][r][l] = acc0[r];
    }
    __syncthreads();

    const int bank = (blockIdx.x & (NBANK - 1)) * 64;
    const int colg = l >> 5;                    // 0/1: which 32-lane group
    if (w == 0) {
        #pragma unroll
        for (int r = 0; r < 16; ++r) {
            float v = acc0[r] + red[1][r][l];
            int row = (r & 3) + 8 * (r >> 2) + 4 * colg;
            out[1 + (size_t)row * C_DIM + c] = v;
            float e = expf(v);
            #pragma unroll
            for (int m = 1; m <= 16; m <<= 1) e += __shfl_xor(e, m);
            if ((l & 31) == 0) atomicAdd(&wsQ[bank + row], e);
        }
    } else {
        #pragma unroll
        for (int r = 0; r < 16; ++r) {
            float v = acc1[r] + red[0][r][l];
            int row = 32 + (r & 3) + 8 * (r >> 2) + 4 * colg;
            out[1 + (size_t)row * C_DIM + c] = v;
            float e = expf(v);
            #pragma unroll
            for (int m = 1; m <= 16; m <<= 1) e += __shfl_xor(e, m);
            if ((l & 31) == 0) atomicAdd(&wsQ[bank + row], e);
        }
    }
}

// ---------------- Kernel C: finalize loss ----------------
__global__ __launch_bounds__(64)
void final_kernel(float* __restrict__ out, const int* __restrict__ targets,
                  const float* __restrict__ wsQ, const float* __restrict__ wsH) {
    int b = threadIdx.x;
    float S = 0.0f;
    #pragma unroll
    for (int k = 0; k < NBANK; ++k) S += wsQ[k * 64 + b];
    float logZ = logf(S);
    int t = targets[b];
    float lb = logZ - out[1 + (size_t)b * C_DIM + t];
    #pragma unroll
    for (int m = 1; m <= 32; m <<= 1) lb += __shfl_xor(lb, m);
    if (b == 0) out[0] = lb * (1.0f / 64.0f) + wsH[0];
}

extern "C" void kernel_launch(void* const* d_in, const int* in_sizes, int n_in,
                              void* d_out, int out_size, void* d_ws, size_t ws_size,
                              hipStream_t stream) {
    (void)in_sizes; (void)n_in; (void)out_size; (void)ws_size;
    const float* X        = (const float*)d_in[0];
    const float* V        = (const float*)d_in[1];
    const int*   targets  = (const int*)d_in[2];
    const int*   pos_idx  = (const int*)d_in[3];
    const int*   pos_mask = (const int*)d_in[4];
    const int*   neg_idx  = (const int*)d_in[5];
    const int*   neg_mask = (const int*)d_in[6];
    float* out = (float*)d_out;
    float*          wsH = (float*)d_ws;                              // 1 float (pad to 64)
    float*          wsQ = (float*)d_ws + 64;                         // NBANK*64 floats
    unsigned short* wsA = (unsigned short*)((char*)d_ws + 8192);     // 32 KB A-fragments

    hipLaunchKernelGGL(prep_kernel, dim3(1), dim3(256), 0, stream,
                       X, pos_idx, pos_mask, neg_idx, neg_mask, wsH, wsA, wsQ);
    hipLaunchKernelGGL(logits_kernel, dim3(NTILE), dim3(128), 0, stream, V, wsA, out, wsQ);
    hipLaunchKernelGGL(final_kernel, dim3(1), dim3(64), 0, stream, out, targets, wsQ, wsH);
}

// Round 4
// 59.604 us; speedup vs baseline: 1.3347x; 1.3347x over previous
//
#include <hip/hip_runtime.h>
#include <hip/hip_bf16.h>
#include <math.h>

#define B_DIM 64
#define D_DIM 256
#define C_DIM 100000
#define P_DIM 8
#define N_DIM 32
#define GBLK 1563       // ceil(C_DIM / 64)
#define RS_SEG 8        // rowsum segments per batch row
#define RS_LEN 12500    // C_DIM / RS_SEG

typedef __attribute__((ext_vector_type(8))) short bf16x8;
typedef __attribute__((ext_vector_type(16))) float f32x16;

__device__ __forceinline__ unsigned short bf16_rn(float f) {
    unsigned int u = __float_as_uint(f);
    unsigned int r = (u + 0x7FFFu + ((u >> 16) & 1u)) >> 16;
    return (unsigned short)r;
}

// Truncate-split: x = hi + lo (hi exact truncation, lo rounds; combined ~2^-17 rel err)
__device__ __forceinline__ void split_bf16(float x, unsigned short& hi, unsigned short& lo) {
    unsigned int bx = __float_as_uint(x);
    unsigned int hb = bx & 0xFFFF0000u;
    hi = (unsigned short)(hb >> 16);
    lo = bf16_rn(x - __uint_as_float(hb));
}

__device__ __forceinline__ float softplusf(float x) { return log1pf(expf(x)); }

__device__ __forceinline__ short f2bf(float x) {
    __hip_bfloat16 b = __float2bfloat16(x);   // pairs into v_cvt_pk_bf16_f32
    return *reinterpret_cast<short*>(&b);
}

// async 16B global->LDS copy; lds base must be wave-uniform (HW adds lane*16)
__device__ __forceinline__ void async_copy16(const float* src, float* lds_base) {
    __builtin_amdgcn_global_load_lds(
        (const __attribute__((address_space(1))) unsigned int*)src,
        (__attribute__((address_space(3))) unsigned int*)lds_base,
        16, 0, 0);
}

// ---------------- Kernel A: norms, sim = ni@ni^T (hi+lo MFMA), hp/hn losses, A-frag precompute ----------------
__global__ __launch_bounds__(256)
void prep_kernel(const float* __restrict__ X,
                 const int* __restrict__ pos_idx, const int* __restrict__ pos_mask,
                 const int* __restrict__ neg_idx, const int* __restrict__ neg_mask,
                 float* __restrict__ wsH, unsigned short* __restrict__ wsA) {
    __shared__ unsigned short fHi[2048 * 8];   // 32 KB: ni hi fragments (frag order)
    __shared__ unsigned short fLo[2048 * 8];   // 32 KB
    __shared__ float sim[64][64];              // 16 KB
    __shared__ float inv[64];
    __shared__ float hp[64];
    __shared__ float contrib[64];
    const int tid = threadIdx.x;
    // row norms: 4 threads per row
    {
        int r = tid >> 2, q = tid & 3;
        const float* row = X + r * D_DIM + q * 64;
        float s = 0.0f;
        #pragma unroll
        for (int i = 0; i < 64; i += 4) {
            float4 v = *(const float4*)(row + i);
            s += v.x * v.x + v.y * v.y + v.z * v.z + v.w * v.w;
        }
        s += __shfl_xor(s, 1);
        s += __shfl_xor(s, 2);
        if (q == 0) inv[r] = 1.0f / fmaxf(sqrtf(s), 1e-12f);
    }
    __syncthreads();
    // fragments: lane l holds M[mt*32+(l&31)][kg*16+8*(l>>5)+j]
    for (int t = tid; t < 2048; t += 256) {
        int l = t & 63, kg = (t >> 6) & 15, mt = t >> 10;
        int row = mt * 32 + (l & 31);
        int col0 = kg * 16 + 8 * (l >> 5);
        const float* src = X + row * D_DIM + col0;
        float iv = inv[row];
        #pragma unroll
        for (int j = 0; j < 8; ++j) {
            unsigned short h, lo;
            split_bf16(src[j] * iv, h, lo);
            fHi[t * 8 + j] = h;
            fLo[t * 8 + j] = lo;
            wsA[t * 8 + j] = (unsigned short)f2bf(src[j]);  // raw-X fragment for logits kernel
        }
    }
    __syncthreads();
    // sim via 4 wave tiles of 32x32 (A-frag and B-frag layouts coincide for ni@ni^T)
    {
        int w = tid >> 6, l = tid & 63;
        int mt = w >> 1, nt = w & 1;
        f32x16 acc;
        #pragma unroll
        for (int i = 0; i < 16; ++i) acc[i] = 0.0f;
        #pragma unroll
        for (int ks = 0; ks < 16; ++ks) {
            const bf16x8 ah = *(const bf16x8*)&fHi[((mt * 16 + ks) * 64 + l) * 8];
            const bf16x8 al = *(const bf16x8*)&fLo[((mt * 16 + ks) * 64 + l) * 8];
            const bf16x8 bh = *(const bf16x8*)&fHi[((nt * 16 + ks) * 64 + l) * 8];
            const bf16x8 bl = *(const bf16x8*)&fLo[((nt * 16 + ks) * 64 + l) * 8];
            acc = __builtin_amdgcn_mfma_f32_32x32x16_bf16(ah, bh, acc, 0, 0, 0);
            acc = __builtin_amdgcn_mfma_f32_32x32x16_bf16(al, bh, acc, 0, 0, 0);
            acc = __builtin_amdgcn_mfma_f32_32x32x16_bf16(ah, bl, acc, 0, 0, 0);
        }
        #pragma unroll
        for (int r = 0; r < 16; ++r) {
            int brow = mt * 32 + (r & 3) + 8 * (r >> 2) + 4 * (l >> 5);
            int bcol = nt * 32 + (l & 31);
            sim[brow][bcol] = acc[r];
        }
    }
    __syncthreads();
    // hardest positive: min over valid positive pairs (>=1 guaranteed)
    {
        int r = tid >> 2, q = tid & 3;
        const float INF = __int_as_float(0x7f800000);
        float m = INF;
        #pragma unroll
        for (int pp = 0; pp < 2; ++pp) {
            int p = q * 2 + pp;
            int j = pos_idx[r * P_DIM + p];
            int msk = pos_mask[r * P_DIM + p];
            float ps = sim[r][j];
            m = fminf(m, msk ? ps : INF);
        }
        m = fminf(m, __shfl_xor(m, 1));
        m = fminf(m, __shfl_xor(m, 2));
        if (q == 0) hp[r] = m;
    }
    __syncthreads();
    // hard negatives
    {
        int r = tid >> 2, q = tid & 3;
        float thr = hp[r] - 0.3f;
        float sum = 0.0f; int cnt = 0;
        #pragma unroll
        for (int nn = 0; nn < 8; ++nn) {
            int n = q * 8 + nn;
            int j = neg_idx[r * N_DIM + n];
            int msk = neg_mask[r * N_DIM + n];
            float ns = sim[r][j];
            if (msk && (ns > thr)) { cnt += 1; sum += softplusf(ns); }
        }
        sum += __shfl_xor(sum, 1); cnt += __shfl_xor(cnt, 1);
        sum += __shfl_xor(sum, 2); cnt += __shfl_xor(cnt, 2);
        if (q == 0) {
            float hn = (cnt > 0) ? (sum / (float)cnt) : 0.0f;
            contrib[r] = softplusf(-hp[r]) + hn;
        }
    }
    __syncthreads();
    if (tid == 0) {
        float s = 0.0f;
        for (int i = 0; i < 64; ++i) s += contrib[i];
        wsH[0] = s * (1.0f / 64.0f);
    }
}

// ---------------- Kernel B: logits = X @ V^T, async-LDS-staged V, chunked K ----------------
// Block = 128 thr (2 waves), 64 V-columns/block, K in 4 chunks of 64.
// LDS: vbuf[2][64 cols][64 k] fp32, 16B-unit XOR-swizzle (unit ^= col&15) applied as
// inverse perm on the GLOBAL source (global_load_lds dest must stay linear).
__global__ __launch_bounds__(128)
void logits_kernel(const float* __restrict__ V, const unsigned short* __restrict__ wsA,
                   float* __restrict__ out) {
    __shared__ float vbuf[2][4096];            // 2 x 16 KB
    const int tid = threadIdx.x;
    const int w = tid >> 6, l = tid & 63;
    const int c0 = blockIdx.x * 64;
    const int col = w * 32 + (l & 31);         // this wave's local column 0..63
    const int hi = l >> 5;

    // ---- staging: chunk kc -> vbuf[b]; 8 wave-issues x 1KB each ----
    #define STAGE(kc, b)                                                          \
        {                                                                         \
            _Pragma("unroll")                                                     \
            for (int j = 0; j < 8; ++j) {                                         \
                int U  = (j * 2 + w) * 64 + l;      /* unit 0..1023 */            \
                int r  = U >> 4;                    /* local col 0..63 */         \
                int up = U & 15;                    /* stored (swizzled) unit */  \
                int u  = up ^ (r & 15);             /* source unit */             \
                int cc = c0 + r; cc = (cc < C_DIM) ? cc : (C_DIM - 1);            \
                const float* src = V + (size_t)cc * D_DIM + (kc) * 64 + u * 4;    \
                async_copy16(src, &vbuf[b][(j * 2 + w) * 256]);                   \
            }                                                                     \
        }

    STAGE(0, 0);
    __syncthreads();

    f32x16 acc0, acc1;
    #pragma unroll
    for (int i = 0; i < 16; ++i) { acc0[i] = 0.0f; acc1[i] = 0.0f; }

    #pragma unroll
    for (int kc = 0; kc < 4; ++kc) {
        if (kc < 3) STAGE(kc + 1, (kc + 1) & 1);
        const int b = kc & 1;
        #pragma unroll
        for (int ks = 0; ks < 4; ++ks) {
            const int kg = kc * 4 + ks;
            const bf16x8 a0 = *(const bf16x8*)(wsA + ((0 * 16 + kg) * 64 + l) * 8);
            const bf16x8 a1 = *(const bf16x8*)(wsA + ((1 * 16 + kg) * 64 + l) * 8);
            const int u0 = ks * 4 + 2 * hi;
            float4 v0 = *(const float4*)&vbuf[b][col * 64 + ((u0    ) ^ (col & 15)) * 4];
            float4 v1 = *(const float4*)&vbuf[b][col * 64 + ((u0 + 1) ^ (col & 15)) * 4];
            bf16x8 vh;
            vh[0] = f2bf(v0.x); vh[1] = f2bf(v0.y); vh[2] = f2bf(v0.z); vh[3] = f2bf(v0.w);
            vh[4] = f2bf(v1.x); vh[5] = f2bf(v1.y); vh[6] = f2bf(v1.z); vh[7] = f2bf(v1.w);
            acc0 = __builtin_amdgcn_mfma_f32_32x32x16_bf16(a0, vh, acc0, 0, 0, 0);
            acc1 = __builtin_amdgcn_mfma_f32_32x32x16_bf16(a1, vh, acc1, 0, 0, 0);
        }
        __syncthreads();   // drains vmcnt: next chunk staged; this buf free for re-stage
    }
    #undef STAGE

    // ---- epilogue: pure coalesced stores (two 128B segments per instr) ----
    const int c = c0 + col;
    if (c < C_DIM) {
        #pragma unroll
        for (int r = 0; r < 16; ++r) {
            int row0 = (r & 3) + 8 * (r >> 2) + 4 * hi;
            out[1 + (size_t)row0 * C_DIM + c] = acc0[r];
            out[1 + (size_t)(row0 + 32) * C_DIM + c] = acc1[r];
        }
    }
}

// ---------------- Kernel C: per-segment exp-sums over the (L2/L3-hot) logits ----------------
__global__ __launch_bounds__(256)
void rowsum_kernel(const float* __restrict__ out, float* __restrict__ wsQ) {
    const int row = blockIdx.x >> 3, seg = blockIdx.x & 7;
    const float* base = out + 1 + (size_t)row * C_DIM + seg * RS_LEN;
    float a0 = 0.f, a1 = 0.f, a2 = 0.f, a3 = 0.f;
    for (int j0 = threadIdx.x; j0 < RS_LEN; j0 += 1024) {
        int j1 = j0 + 256, j2 = j0 + 512, j3 = j0 + 768;
        a0 += expf(base[j0]);
        if (j1 < RS_LEN) a1 += expf(base[j1]);
        if (j2 < RS_LEN) a2 += expf(base[j2]);
        if (j3 < RS_LEN) a3 += expf(base[j3]);
    }
    float s = (a0 + a1) + (a2 + a3);
    #pragma unroll
    for (int m = 1; m <= 32; m <<= 1) s += __shfl_xor(s, m);
    __shared__ float ps[4];
    if ((threadIdx.x & 63) == 0) ps[threadIdx.x >> 6] = s;
    __syncthreads();
    if (threadIdx.x == 0) wsQ[blockIdx.x] = (ps[0] + ps[1]) + (ps[2] + ps[3]);
}

// ---------------- Kernel D: finalize loss ----------------
__global__ __launch_bounds__(64)
void final_kernel(float* __restrict__ out, const int* __restrict__ targets,
                  const float* __restrict__ wsQ, const float* __restrict__ wsH) {
    int b = threadIdx.x;
    float S = 0.0f;
    #pragma unroll
    for (int s = 0; s < 8; ++s) S += wsQ[b * 8 + s];
    float logZ = logf(S);
    int t = targets[b];
    float lb = logZ - out[1 + (size_t)b * C_DIM + t];
    #pragma unroll
    for (int m = 1; m <= 32; m <<= 1) lb += __shfl_xor(lb, m);
    if (b == 0) out[0] = lb * (1.0f / 64.0f) + wsH[0];
}

extern "C" void kernel_launch(void* const* d_in, const int* in_sizes, int n_in,
                              void* d_out, int out_size, void* d_ws, size_t ws_size,
                              hipStream_t stream) {
    (void)in_sizes; (void)n_in; (void)out_size; (void)ws_size;
    const float* X        = (const float*)d_in[0];
    const float* V        = (const float*)d_in[1];
    const int*   targets  = (const int*)d_in[2];
    const int*   pos_idx  = (const int*)d_in[3];
    const int*   pos_mask = (const int*)d_in[4];
    const int*   neg_idx  = (const int*)d_in[5];
    const int*   neg_mask = (const int*)d_in[6];
    float* out = (float*)d_out;
    float*          wsH = (float*)d_ws;                              // 1 float (pad to 64)
    float*          wsQ = (float*)d_ws + 64;                         // 512 floats
    unsigned short* wsA = (unsigned short*)((char*)d_ws + 8192);     // 32 KB A-fragments

    hipLaunchKernelGGL(prep_kernel, dim3(1), dim3(256), 0, stream,
                       X, pos_idx, pos_mask, neg_idx, neg_mask, wsH, wsA);
    hipLaunchKernelGGL(logits_kernel, dim3(GBLK), dim3(128), 0, stream, V, wsA, out);
    hipLaunchKernelGGL(rowsum_kernel, dim3(B_DIM * RS_SEG), dim3(256), 0, stream, out, wsQ);
    hipLaunchKernelGGL(final_kernel, dim3(1), dim3(64), 0, stream, out, targets, wsQ, wsH);
}